// Round 1
// baseline (293.112 us; speedup 1.0000x reference)
//
#include <hip/hip_runtime.h>
#include <hip/hip_bf16.h>

#define IN_F 8192
#define OUT_F 8192
#define SEQ 64
#define LORA_R 16
#define SCALING 2.0f

typedef __attribute__((ext_vector_type(8))) short bf16x8;
typedef __attribute__((ext_vector_type(4))) float f32x4;
typedef __attribute__((ext_vector_type(4))) int i32x4;

__device__ __forceinline__ short f2bf(float f) {
    unsigned u = __builtin_bit_cast(unsigned, f);
    u += 0x7fffu + ((u >> 16) & 1u);   // round-to-nearest-even
    return (short)(u >> 16);
}

// Prep: cast x (fp32) -> bf16 into ws, and compute t = x @ A^T (64x16) via
// K-split partial sums + global atomics. 64 blocks, one 128-wide K chunk each.
__global__ __launch_bounds__(256) void k_prep(
    const float* __restrict__ x, const float* __restrict__ A,
    unsigned short* __restrict__ xb, float* __restrict__ t) {
    __shared__ float xs[SEQ][129];
    __shared__ float as[LORA_R][129];
    const int k0 = blockIdx.x * 128;
    const int tid = threadIdx.x;

    for (int idx = tid; idx < SEQ * 128; idx += 256) {
        int s = idx >> 7, kk = idx & 127;
        float v = x[s * IN_F + k0 + kk];
        xs[s][kk] = v;
        xb[s * IN_F + k0 + kk] = (unsigned short)f2bf(v);
    }
    for (int idx = tid; idx < LORA_R * 128; idx += 256) {
        int r = idx >> 7, kk = idx & 127;
        as[r][kk] = A[r * IN_F + k0 + kk];
    }
    __syncthreads();

    #pragma unroll
    for (int pp = 0; pp < 4; ++pp) {
        int p = tid + pp * 256;          // p = s*16 + r
        int s = p >> 4, r = p & 15;
        float acc = 0.f;
        for (int kk = 0; kk < 128; ++kk) acc += xs[s][kk] * as[r][kk];
        atomicAdd(&t[s * LORA_R + r], acc);
    }
}

// Main: one block per 16-wide output-column tile (512 blocks, 256 thr = 4 waves).
// Each wave takes a 2048-wide K chunk, holds all 4 m-tiles (M=64) in acc.
// B-operand = dequantized W rows; A-operand = bf16 x from ws.
__global__ __launch_bounds__(256) void k_main(
    const int* __restrict__ packed, const float* __restrict__ scales,
    const unsigned short* __restrict__ xb, const float* __restrict__ t,
    const float* __restrict__ B, float* __restrict__ out) {
    const int n0 = blockIdx.x * 16;
    const int tid = threadIdx.x;
    const int w = tid >> 6;          // wave id -> K chunk
    const int lane = tid & 63;
    const int quad = lane >> 4;
    const int row16 = lane & 15;
    const int o = n0 + row16;

    __shared__ float accs[4][SEQ * 16];

    f32x4 acc[4];
    #pragma unroll
    for (int mt = 0; mt < 4; ++mt) acc[mt] = (f32x4){0.f, 0.f, 0.f, 0.f};

    const int kbase = w * 2048;
    const int* __restrict__ prow = packed + (long)o * (IN_F / 2);
    const float* __restrict__ srow = scales + o * (IN_F / 64);

    for (int ks = 0; ks < 64; ++ks) {
        const int k0 = kbase + ks * 32;
        const int i0 = k0 + quad * 8;

        // --- dequant 8 weights of row o, k = i0..i0+7 ---
        i32x4 pv = *(const i32x4*)(prow + (i0 >> 1));
        float sc = srow[i0 >> 6];
        float s8 = sc * -8.0f;
        bf16x8 bfrag;
        #pragma unroll
        for (int m = 0; m < 4; ++m) {
            int v = pv[m];
            float w0 = fmaf((float)(v & 15), sc, s8);
            float w1 = fmaf((float)((v >> 4) & 15), sc, s8);
            bfrag[2 * m]     = f2bf(w0);
            bfrag[2 * m + 1] = f2bf(w1);
        }

        // --- 4 m-tiles of x against this W fragment ---
        #pragma unroll
        for (int mt = 0; mt < 4; ++mt) {
            bf16x8 afrag = *(const bf16x8*)(xb + (mt * 16 + row16) * IN_F + i0);
            acc[mt] = __builtin_amdgcn_mfma_f32_16x16x32_bf16(afrag, bfrag, acc[mt], 0, 0, 0);
        }
    }

    // stash per-wave partials: C/D layout row = quad*4+r, col = row16
    float* myacc = accs[w];
    #pragma unroll
    for (int mt = 0; mt < 4; ++mt)
        #pragma unroll
        for (int r = 0; r < 4; ++r)
            myacc[(mt * 16 + quad * 4 + r) * 16 + row16] = acc[mt][r];
    __syncthreads();

    // epilogue: reduce 4 waves + LoRA, write each output once (no pre-zero needed)
    #pragma unroll
    for (int pp = 0; pp < 4; ++pp) {
        int p = tid + pp * 256;          // p = s*16 + c
        int s = p >> 4, c = p & 15;
        float v = accs[0][s * 16 + c] + accs[1][s * 16 + c] +
                  accs[2][s * 16 + c] + accs[3][s * 16 + c];
        float lora = 0.f;
        #pragma unroll
        for (int r = 0; r < LORA_R; ++r)
            lora += t[s * LORA_R + r] * B[(n0 + c) * LORA_R + r];
        out[s * OUT_F + n0 + c] = v + SCALING * lora;
    }
}

extern "C" void kernel_launch(void* const* d_in, const int* in_sizes, int n_in,
                              void* d_out, int out_size, void* d_ws, size_t ws_size,
                              hipStream_t stream) {
    const float* x      = (const float*)d_in[0];
    const int* packed   = (const int*)d_in[1];
    const float* scales = (const float*)d_in[2];
    const float* lora_A = (const float*)d_in[3];
    const float* lora_B = (const float*)d_in[4];
    float* out = (float*)d_out;

    unsigned short* xb = (unsigned short*)d_ws;                 // 64*8192*2 = 1 MiB
    float* t = (float*)((char*)d_ws + (size_t)SEQ * IN_F * 2);  // 64*16*4 = 4 KiB

    hipMemsetAsync(t, 0, SEQ * LORA_R * sizeof(float), stream);
    k_prep<<<64, 256, 0, stream>>>(x, lora_A, xb, t);
    k_main<<<512, 256, 0, stream>>>(packed, scales, xb, t, lora_B, out);
}

// Round 2
// 283.042 us; speedup vs baseline: 1.0356x; 1.0356x over previous
//
#include <hip/hip_runtime.h>
#include <hip/hip_bf16.h>

#define IN_F 8192
#define OUT_F 8192
#define SEQ 64
#define LORA_R 16
#define SCALING 2.0f

typedef __attribute__((ext_vector_type(8))) short bf16x8;
typedef __attribute__((ext_vector_type(4))) float f32x4;
typedef __attribute__((ext_vector_type(4))) int i32x4;
typedef __attribute__((ext_vector_type(4))) unsigned short u16x4;

__device__ __forceinline__ short f2bf(float f) {
    unsigned u = __builtin_bit_cast(unsigned, f);
    u += 0x7fffu + ((u >> 16) & 1u);   // round-to-nearest-even
    return (short)(u >> 16);
}

// Cast x (fp32) -> bf16 into ws. 64 blocks x 256 thr, grid-stride float4.
__global__ __launch_bounds__(256) void k_cast(
    const float* __restrict__ x, unsigned short* __restrict__ xb) {
    const int nvec = SEQ * IN_F / 4;   // 131072
    for (int i = blockIdx.x * 256 + threadIdx.x; i < nvec; i += 64 * 256) {
        f32x4 v = *(const f32x4*)(x + i * 4);
        u16x4 o;
        o.x = (unsigned short)f2bf(v.x);
        o.y = (unsigned short)f2bf(v.y);
        o.z = (unsigned short)f2bf(v.z);
        o.w = (unsigned short)f2bf(v.w);
        *(u16x4*)(xb + i * 4) = o;
    }
}

// t = x @ A^T : one wave per output element (64*16 = 1024 waves = 256 blocks x 4 waves)
__global__ __launch_bounds__(256) void k_lora_t(
    const float* __restrict__ x, const float* __restrict__ A,
    float* __restrict__ t) {
    const int wid = blockIdx.x * 4 + (threadIdx.x >> 6);  // 0..1023
    const int lane = threadIdx.x & 63;
    const int s = wid >> 4, r = wid & 15;
    const float* __restrict__ xr = x + s * IN_F;
    const float* __restrict__ ar = A + r * IN_F;
    float acc = 0.f;
    #pragma unroll
    for (int j = 0; j < 32; ++j) {
        const int idx = j * 256 + lane * 4;
        f32x4 xv = *(const f32x4*)(xr + idx);
        f32x4 av = *(const f32x4*)(ar + idx);
        acc = fmaf(xv.x, av.x, acc);
        acc = fmaf(xv.y, av.y, acc);
        acc = fmaf(xv.z, av.z, acc);
        acc = fmaf(xv.w, av.w, acc);
    }
    #pragma unroll
    for (int off = 32; off > 0; off >>= 1)
        acc += __shfl_down(acc, off, 64);
    if (lane == 0) t[s * LORA_R + r] = acc;
}

__device__ __forceinline__ bf16x8 dequant8(i32x4 pv, float sc) {
    float s8 = sc * -8.0f;
    bf16x8 b;
    #pragma unroll
    for (int m = 0; m < 4; ++m) {
        int v = pv[m];
        b[2 * m]     = f2bf(fmaf((float)(v & 15), sc, s8));
        b[2 * m + 1] = f2bf(fmaf((float)((v >> 4) & 15), sc, s8));
    }
    return b;
}

// Main: 512 blocks (one per 16-col n-tile) x 512 thr (8 waves, 8-way K split).
// Per wave: K-chunk of 1024 = 32 k-steps; depth-1 prefetch of packed/scale/x.
__global__ __launch_bounds__(512) void k_main(
    const int* __restrict__ packed, const float* __restrict__ scales,
    const unsigned short* __restrict__ xb, const float* __restrict__ t,
    const float* __restrict__ B, float* __restrict__ out) {
    const int n0 = blockIdx.x * 16;
    const int tid = threadIdx.x;
    const int w = tid >> 6;          // wave id 0..7 -> K chunk
    const int lane = tid & 63;
    const int quad = lane >> 4;
    const int row16 = lane & 15;
    const int o = n0 + row16;

    __shared__ float accs[8][SEQ * 17];   // pad 16->17 to break bank conflicts

    f32x4 acc[4];
    #pragma unroll
    for (int mt = 0; mt < 4; ++mt) acc[mt] = (f32x4){0.f, 0.f, 0.f, 0.f};

    const int* __restrict__ prow = packed + (long)o * (IN_F / 2);
    const float* __restrict__ srow = scales + o * (IN_F / 64);
    const unsigned short* __restrict__ xbase = xb + row16 * IN_F;

    int i0 = w * 1024 + quad * 8;
    i32x4 pv = *(const i32x4*)(prow + (i0 >> 1));
    float sc = srow[i0 >> 6];
    bf16x8 af[4];
    #pragma unroll
    for (int mt = 0; mt < 4; ++mt)
        af[mt] = *(const bf16x8*)(xbase + mt * 16 * IN_F + i0);

    for (int ks = 0; ks < 31; ++ks) {
        const int i1 = i0 + 32;
        // prefetch next step
        i32x4 pv_n = *(const i32x4*)(prow + (i1 >> 1));
        float sc_n = srow[i1 >> 6];
        bf16x8 af_n[4];
        #pragma unroll
        for (int mt = 0; mt < 4; ++mt)
            af_n[mt] = *(const bf16x8*)(xbase + mt * 16 * IN_F + i1);
        // compute current
        bf16x8 bfrag = dequant8(pv, sc);
        #pragma unroll
        for (int mt = 0; mt < 4; ++mt)
            acc[mt] = __builtin_amdgcn_mfma_f32_16x16x32_bf16(af[mt], bfrag, acc[mt], 0, 0, 0);
        // rotate
        i0 = i1; pv = pv_n; sc = sc_n;
        #pragma unroll
        for (int mt = 0; mt < 4; ++mt) af[mt] = af_n[mt];
    }
    {
        bf16x8 bfrag = dequant8(pv, sc);
        #pragma unroll
        for (int mt = 0; mt < 4; ++mt)
            acc[mt] = __builtin_amdgcn_mfma_f32_16x16x32_bf16(af[mt], bfrag, acc[mt], 0, 0, 0);
    }

    // stash per-wave partials: C/D layout row = quad*4+r, col = row16
    float* myacc = accs[w];
    #pragma unroll
    for (int mt = 0; mt < 4; ++mt)
        #pragma unroll
        for (int r = 0; r < 4; ++r)
            myacc[(mt * 16 + quad * 4 + r) * 17 + row16] = acc[mt][r];
    __syncthreads();

    // epilogue: each thread reduces 2 outputs across 8 waves + LoRA
    #pragma unroll
    for (int pp = 0; pp < 2; ++pp) {
        int p = tid + pp * 512;          // p = s*16 + c
        int s = p >> 4, c = p & 15;
        float v = 0.f;
        #pragma unroll
        for (int ww = 0; ww < 8; ++ww) v += accs[ww][s * 17 + c];
        float lora = 0.f;
        #pragma unroll
        for (int r = 0; r < LORA_R; ++r)
            lora += t[s * LORA_R + r] * B[(n0 + c) * LORA_R + r];
        out[s * OUT_F + n0 + c] = v + SCALING * lora;
    }
}

extern "C" void kernel_launch(void* const* d_in, const int* in_sizes, int n_in,
                              void* d_out, int out_size, void* d_ws, size_t ws_size,
                              hipStream_t stream) {
    const float* x      = (const float*)d_in[0];
    const int* packed   = (const int*)d_in[1];
    const float* scales = (const float*)d_in[2];
    const float* lora_A = (const float*)d_in[3];
    const float* lora_B = (const float*)d_in[4];
    float* out = (float*)d_out;

    unsigned short* xb = (unsigned short*)d_ws;                 // 64*8192*2 = 1 MiB
    float* t = (float*)((char*)d_ws + (size_t)SEQ * IN_F * 2);  // 64*16*4 = 4 KiB

    k_cast<<<64, 256, 0, stream>>>(x, xb);
    k_lora_t<<<256, 256, 0, stream>>>(x, lora_A, t);
    k_main<<<512, 512, 0, stream>>>(packed, scales, xb, t, lora_B, out);
}

// Round 3
// 241.592 us; speedup vs baseline: 1.2133x; 1.1716x over previous
//
#include <hip/hip_runtime.h>
#include <hip/hip_bf16.h>

#define IN_F 8192
#define OUT_F 8192
#define SEQ 64
#define LORA_R 16

typedef __attribute__((ext_vector_type(4))) float f32x4;
typedef __attribute__((ext_vector_type(4))) int i32x4;
typedef __attribute__((ext_vector_type(8))) unsigned short u16x8;
typedef _Float16 f16x2 __attribute__((ext_vector_type(2)));
typedef _Float16 f16x8 __attribute__((ext_vector_type(8)));

// ---------- prep: cast x -> fp16 (ws) and t = x @ A^T (fp32, split-K atomics) ----------
__global__ __launch_bounds__(256) void k_prep(
    const float* __restrict__ x, const float* __restrict__ A,
    unsigned short* __restrict__ xb, float* __restrict__ t) {
    __shared__ float xs[SEQ][132];     // fp32 x chunk, padded stride
    __shared__ float as[LORA_R][132];  // fp32 A chunk
    const int tid = threadIdx.x;
    const int k0 = blockIdx.x * 128;   // 64 blocks x 128-wide K chunks

    // x chunk: 64 rows x 128 cols = 1024 granules of 8 floats; 4 per thread
    #pragma unroll
    for (int j = 0; j < 4; ++j) {
        int gi = tid + j * 256;
        int row = gi >> 4, g = gi & 15;
        const float* src = x + row * IN_F + k0 + g * 8;
        f32x4 v0 = *(const f32x4*)src;
        f32x4 v1 = *(const f32x4*)(src + 4);
        *(f32x4*)&xs[row][g * 8]     = v0;
        *(f32x4*)&xs[row][g * 8 + 4] = v1;
        u16x8 h;
        h[0] = __builtin_bit_cast(unsigned short, (_Float16)v0.x);
        h[1] = __builtin_bit_cast(unsigned short, (_Float16)v0.y);
        h[2] = __builtin_bit_cast(unsigned short, (_Float16)v0.z);
        h[3] = __builtin_bit_cast(unsigned short, (_Float16)v0.w);
        h[4] = __builtin_bit_cast(unsigned short, (_Float16)v1.x);
        h[5] = __builtin_bit_cast(unsigned short, (_Float16)v1.y);
        h[6] = __builtin_bit_cast(unsigned short, (_Float16)v1.z);
        h[7] = __builtin_bit_cast(unsigned short, (_Float16)v1.w);
        *(u16x8*)(xb + row * IN_F + k0 + g * 8) = h;
    }
    // A chunk: 16 rows x 128 = 256 granules; 1 per thread
    {
        int row = tid >> 4, g = tid & 15;
        const float* src = A + row * IN_F + k0 + g * 8;
        f32x4 v0 = *(const f32x4*)src;
        f32x4 v1 = *(const f32x4*)(src + 4);
        *(f32x4*)&as[row][g * 8]     = v0;
        *(f32x4*)&as[row][g * 8 + 4] = v1;
    }
    __syncthreads();

    // t partials: 1024 (s,r) outputs, 4 per thread, 128-deep dot each
    #pragma unroll
    for (int j = 0; j < 4; ++j) {
        int p = tid + j * 256;
        int s = p >> 4, r = p & 15;
        float acc = 0.f;
        #pragma unroll 8
        for (int k = 0; k < 128; ++k) acc = fmaf(xs[s][k], as[r][k], acc);
        atomicAdd(&t[s * LORA_R + r], acc);
    }
}

// ---------- main: 512 blocks x 256 thr; N-tile 16, BK 128, double-buffered LDS ----------
// LDS layout (51968 B):
//   xs  : [2][64][136] _Float16   (0      .. 34816)   x tile, stride 136 halves
//   wt  : [2][16][68]  int        (34816  .. 43520)   packed W tile, stride 68 ints
//   scs : [16][132]    float      (43520  .. 51968)   all scales for this block's rows
//   accs: [4][64][17]  float      alias over xs buf0 (epilogue only)
__global__ __launch_bounds__(256) void k_main(
    const int* __restrict__ packed, const float* __restrict__ scales,
    const unsigned short* __restrict__ xb, const float* __restrict__ t,
    const float* __restrict__ B, float* __restrict__ out) {
    __shared__ char lds_raw[51968];
    _Float16* xs  = (_Float16*)lds_raw;
    int*      wt  = (int*)(lds_raw + 34816);
    float*    scs = (float*)(lds_raw + 43520);
    float*    accs = (float*)lds_raw;

    const int tid = threadIdx.x;
    const int n0 = blockIdx.x * 16;
    const int wk = tid >> 6;     // wave id -> k32 sub-chunk within BK
    const int lane = tid & 63;
    const int q = lane >> 4;
    const int c16 = lane & 15;

    // stage all scales for rows n0..n0+15 (16 x 128 fp32), once
    {
        int row = tid >> 4, g = tid & 15;
        const float* src = scales + (n0 + row) * (IN_F / 64) + g * 8;
        f32x4 v0 = *(const f32x4*)src;
        f32x4 v1 = *(const f32x4*)(src + 4);
        *(f32x4*)&scs[row * 132 + g * 8]     = v0;
        *(f32x4*)&scs[row * 132 + g * 8 + 4] = v1;
    }

    const int xrow = tid >> 4;        // staging coords reused every iter
    const int xg   = tid & 15;

    f32x4 acc[4];
    #pragma unroll
    for (int mt = 0; mt < 4; ++mt) acc[mt] = (f32x4){0.f, 0.f, 0.f, 0.f};

    u16x8 gx[4];
    i32x4 gw;

    // prologue: load + store iter 0
    #pragma unroll
    for (int j = 0; j < 4; ++j) {
        int gi = tid + j * 256;
        int row = gi >> 4, g = gi & 15;
        gx[j] = *(const u16x8*)(xb + row * IN_F + g * 8);
    }
    gw = *(const i32x4*)(packed + (long)(n0 + xrow) * (IN_F / 2) + xg * 4);
    #pragma unroll
    for (int j = 0; j < 4; ++j) {
        int gi = tid + j * 256;
        int row = gi >> 4, g = gi & 15;
        *(u16x8*)((unsigned short*)xs + row * 136 + g * 8) = gx[j];
    }
    *(i32x4*)(wt + xrow * 68 + xg * 4) = gw;
    __syncthreads();

    const f16x2 c1032 = {(_Float16)1032.0f, (_Float16)1032.0f};

    for (int kt = 0; kt < 64; ++kt) {
        const int cur = kt & 1;
        // prefetch next iter into regs (coalesced: per-wave contiguous segments)
        if (kt < 63) {
            #pragma unroll
            for (int j = 0; j < 4; ++j) {
                int gi = tid + j * 256;
                int row = gi >> 4, g = gi & 15;
                gx[j] = *(const u16x8*)(xb + row * IN_F + (kt + 1) * 128 + g * 8);
            }
            gw = *(const i32x4*)(packed + (long)(n0 + xrow) * (IN_F / 2) + (kt + 1) * 64 + xg * 4);
        }

        // ---- compute current buffer ----
        i32x4 pv = *(const i32x4*)(wt + cur * (16 * 68) + c16 * 68 + wk * 16 + q * 4);
        float scf = scs[c16 * 132 + kt * 2 + (wk >> 1)];
        _Float16 sch = (_Float16)scf;
        f16x2 sc2 = {sch, sch};
        f16x8 bf;
        #pragma unroll
        for (int m = 0; m < 4; ++m) {
            unsigned u = ((((unsigned)pv[m] << 12) | (unsigned)pv[m]) & 0x000F000Fu) | 0x64006400u;
            f16x2 h = __builtin_bit_cast(f16x2, u);
            h = (h - c1032) * sc2;      // exact (q-8), then scale
            bf[2 * m]     = h.x;
            bf[2 * m + 1] = h.y;
        }
        const _Float16* xbase = xs + cur * (64 * 136) + wk * 32 + q * 8;
        #pragma unroll
        for (int mt = 0; mt < 4; ++mt) {
            f16x8 af = *(const f16x8*)(xbase + (mt * 16 + c16) * 136);
            acc[mt] = __builtin_amdgcn_mfma_f32_16x16x32_f16(af, bf, acc[mt], 0, 0, 0);
        }
        __syncthreads();
        if (kt < 63) {
            #pragma unroll
            for (int j = 0; j < 4; ++j) {
                int gi = tid + j * 256;
                int row = gi >> 4, g = gi & 15;
                *(u16x8*)((unsigned short*)xs + (1 - cur) * (64 * 136) + row * 136 + g * 8) = gx[j];
            }
            *(i32x4*)(wt + (1 - cur) * (16 * 68) + xrow * 68 + xg * 4) = gw;
        }
        __syncthreads();
    }

    // ---- epilogue: cross-wave reduce (LDS alias) + LoRA ----
    #pragma unroll
    for (int mt = 0; mt < 4; ++mt)
        #pragma unroll
        for (int r = 0; r < 4; ++r)
            accs[(wk * 64 + mt * 16 + q * 4 + r) * 17 + c16] = acc[mt][r];
    __syncthreads();

    #pragma unroll
    for (int j = 0; j < 4; ++j) {
        int p = tid + j * 256;
        int s = p >> 4, c = p & 15;
        float v = accs[(0 * 64 + s) * 17 + c] + accs[(1 * 64 + s) * 17 + c] +
                  accs[(2 * 64 + s) * 17 + c] + accs[(3 * 64 + s) * 17 + c];
        float lr = 0.f;
        #pragma unroll
        for (int r = 0; r < LORA_R; ++r)
            lr += t[s * LORA_R + r] * B[(n0 + c) * LORA_R + r];
        out[s * OUT_F + n0 + c] = v + 2.0f * lr;
    }
}

extern "C" void kernel_launch(void* const* d_in, const int* in_sizes, int n_in,
                              void* d_out, int out_size, void* d_ws, size_t ws_size,
                              hipStream_t stream) {
    const float* x      = (const float*)d_in[0];
    const int* packed   = (const int*)d_in[1];
    const float* scales = (const float*)d_in[2];
    const float* lora_A = (const float*)d_in[3];
    const float* lora_B = (const float*)d_in[4];
    float* out = (float*)d_out;

    unsigned short* xb = (unsigned short*)d_ws;                 // 64*8192*2 = 1 MiB
    float* t = (float*)((char*)d_ws + (size_t)SEQ * IN_F * 2);  // 4 KiB

    hipMemsetAsync(t, 0, SEQ * LORA_R * sizeof(float), stream);
    k_prep<<<64, 256, 0, stream>>>(x, lora_A, xb, t);
    k_main<<<512, 256, 0, stream>>>(packed, scales, xb, t, lora_B, out);
}

// Round 4
// 234.026 us; speedup vs baseline: 1.2525x; 1.0323x over previous
//
#include <hip/hip_runtime.h>
#include <hip/hip_bf16.h>

#define IN_F 8192
#define OUT_F 8192
#define SEQ 64
#define LORA_R 16
#define KH 4096            // K per split-K half

typedef __attribute__((ext_vector_type(4))) float f32x4;
typedef __attribute__((ext_vector_type(4))) int i32x4;
typedef __attribute__((ext_vector_type(8))) unsigned short u16x8;
typedef __attribute__((ext_vector_type(4))) unsigned short u16x4;
typedef _Float16 f16x2 __attribute__((ext_vector_type(2)));
typedef _Float16 f16x8 __attribute__((ext_vector_type(8)));

// ---- prep (fused): xb = fp16(x); t = x @ A^T. One block per s-row. ----
__global__ __launch_bounds__(256) void k_prep(
    const float* __restrict__ x, const float* __restrict__ A,
    unsigned short* __restrict__ xb, float* __restrict__ t) {
    __shared__ float part[64];
    const int s = blockIdx.x;
    const int w = threadIdx.x >> 6, lane = threadIdx.x & 63;
    const int kbase = w * 2048;             // 4 waves x 2048-wide K chunks
    const float* xr = x + s * IN_F + kbase;

    f32x4 xv[8];
    #pragma unroll
    for (int j = 0; j < 8; ++j) {
        xv[j] = *(const f32x4*)(xr + j * 256 + lane * 4);
        u16x4 h;
        h[0] = __builtin_bit_cast(unsigned short, (_Float16)xv[j].x);
        h[1] = __builtin_bit_cast(unsigned short, (_Float16)xv[j].y);
        h[2] = __builtin_bit_cast(unsigned short, (_Float16)xv[j].z);
        h[3] = __builtin_bit_cast(unsigned short, (_Float16)xv[j].w);
        *(u16x4*)(xb + s * IN_F + kbase + j * 256 + lane * 4) = h;
    }

    float acc[LORA_R];
    #pragma unroll
    for (int r = 0; r < LORA_R; ++r) acc[r] = 0.f;
    #pragma unroll
    for (int r = 0; r < LORA_R; ++r) {
        const float* ar = A + r * IN_F + kbase;
        #pragma unroll
        for (int j = 0; j < 8; ++j) {
            f32x4 av = *(const f32x4*)(ar + j * 256 + lane * 4);
            acc[r] = fmaf(xv[j].x, av.x, acc[r]);
            acc[r] = fmaf(xv[j].y, av.y, acc[r]);
            acc[r] = fmaf(xv[j].z, av.z, acc[r]);
            acc[r] = fmaf(xv[j].w, av.w, acc[r]);
        }
    }
    #pragma unroll
    for (int r = 0; r < LORA_R; ++r) {
        float v = acc[r];
        #pragma unroll
        for (int off = 32; off; off >>= 1) v += __shfl_down(v, off, 64);
        if (lane == 0) part[w * 16 + r] = v;
    }
    __syncthreads();
    if (threadIdx.x < 16)
        t[s * LORA_R + threadIdx.x] = part[threadIdx.x] + part[16 + threadIdx.x] +
                                      part[32 + threadIdx.x] + part[48 + threadIdx.x];
}

// ---- main: 512 blocks = 256 n-tiles(32 cols) x 2 K-halves; 512 thr = 8 waves ----
// waves: (nh = w>>2) n-half, (wkk = w&3) k32 sub-step of the BK=128 chunk.
// LDS (60928 B): xs [2][64*136] f16 | wt [2][32*68] int | scs [32*68] f32
// epilogue alias: accs [8][64*17] f32 over xs.
__global__ __launch_bounds__(512, 4) void k_main(
    const int* __restrict__ packed, const float* __restrict__ scales,
    const unsigned short* __restrict__ xb, const float* __restrict__ t,
    const float* __restrict__ B, float* __restrict__ out) {
    __shared__ char lds[60928];
    _Float16* xs = (_Float16*)lds;
    int* wt = (int*)(lds + 34816);
    float* scs = (float*)(lds + 52224);
    float* accs = (float*)lds;

    const int tid = threadIdx.x;
    const int n0 = (blockIdx.x >> 1) * 32;
    const int kh = blockIdx.x & 1;
    const int w = tid >> 6, lane = tid & 63;
    const int nh = w >> 2, wkk = w & 3;
    const int q = lane >> 4, c16 = lane & 15;

    // scales for this block's 32 rows, this K-half (64 blocks each), staged once
    {
        int row = tid >> 4, g = tid & 15;
        f32x4 v = *(const f32x4*)(scales + (n0 + row) * (IN_F / 64) + kh * 64 + g * 4);
        *(f32x4*)(scs + row * 68 + g * 4) = v;
    }

    // staging coords
    const int xrow = tid >> 3, xseg = tid & 7;   // 64 rows x 8 segs x 16 halves
    const int wrow = tid >> 4, wg = tid & 15;    // 32 rows x 16 segs x 4 ints
    const unsigned short* xsrc = xb + xrow * IN_F + kh * KH + xseg * 16;
    const int* wsrc = packed + (long)(n0 + wrow) * (IN_F / 2) + kh * (KH / 2) + wg * 4;

    f32x4 acc[4];
    #pragma unroll
    for (int mt = 0; mt < 4; ++mt) acc[mt] = (f32x4){0.f, 0.f, 0.f, 0.f};

    u16x8 gx0, gx1; i32x4 gw;
    gx0 = *(const u16x8*)(xsrc);
    gx1 = *(const u16x8*)(xsrc + 8);
    gw  = *(const i32x4*)(wsrc);
    *(u16x8*)(xs + xrow * 136 + xseg * 16)     = gx0;
    *(u16x8*)(xs + xrow * 136 + xseg * 16 + 8) = gx1;
    *(i32x4*)(wt + wrow * 68 + wg * 4)         = gw;
    __syncthreads();

    const f16x2 c1032 = {(_Float16)1032.0f, (_Float16)1032.0f};

    for (int kt = 0; kt < 32; ++kt) {
        const int cur = kt & 1;
        if (kt < 31) {   // prefetch next BK chunk (coalesced 256B segments)
            gx0 = *(const u16x8*)(xsrc + (kt + 1) * 128);
            gx1 = *(const u16x8*)(xsrc + (kt + 1) * 128 + 8);
            gw  = *(const i32x4*)(wsrc + (kt + 1) * 64);
        }
        // compute current buffer
        i32x4 pv = *(const i32x4*)(wt + cur * (32 * 68) + (nh * 16 + c16) * 68 + wkk * 16 + q * 4);
        float scf = scs[(nh * 16 + c16) * 68 + kt * 2 + (wkk >> 1)];
        _Float16 sch = (_Float16)scf;
        f16x2 sc2 = {sch, sch};
        f16x8 bf;
        #pragma unroll
        for (int m = 0; m < 4; ++m) {
            unsigned u = ((((unsigned)pv[m] << 12) | (unsigned)pv[m]) & 0x000F000Fu) | 0x64006400u;
            f16x2 h = __builtin_bit_cast(f16x2, u);
            h = (h - c1032) * sc2;          // exact (q-8)*scale
            bf[2 * m] = h.x;
            bf[2 * m + 1] = h.y;
        }
        const _Float16* xbase = xs + cur * (64 * 136) + wkk * 32 + q * 8;
        #pragma unroll
        for (int mt = 0; mt < 4; ++mt) {
            f16x8 af = *(const f16x8*)(xbase + (mt * 16 + c16) * 136);
            acc[mt] = __builtin_amdgcn_mfma_f32_16x16x32_f16(af, bf, acc[mt], 0, 0, 0);
        }
        __syncthreads();
        if (kt < 31) {
            *(u16x8*)(xs + (1 - cur) * (64 * 136) + xrow * 136 + xseg * 16)     = gx0;
            *(u16x8*)(xs + (1 - cur) * (64 * 136) + xrow * 136 + xseg * 16 + 8) = gx1;
            *(i32x4*)(wt + (1 - cur) * (32 * 68) + wrow * 68 + wg * 4)          = gw;
        }
        __syncthreads();
    }

    // epilogue: per-wave partials -> LDS (alias), reduce 4 k-waves, LoRA (kh0), atomic out
    float* myacc = accs + w * (64 * 17);
    #pragma unroll
    for (int mt = 0; mt < 4; ++mt)
        #pragma unroll
        for (int r = 0; r < 4; ++r)
            myacc[(mt * 16 + q * 4 + r) * 17 + c16] = acc[mt][r];
    __syncthreads();

    #pragma unroll
    for (int j = 0; j < 4; ++j) {
        int p = tid + j * 512;                    // 2048 outputs: s in 0..63, c in 0..31
        int s = p >> 5, c = p & 31;
        const float* ab = accs + (c >> 4) * 4 * (64 * 17) + s * 17 + (c & 15);
        float v = ab[0] + ab[64 * 17] + ab[2 * 64 * 17] + ab[3 * 64 * 17];
        if (kh == 0) {
            const float* tp = t + s * LORA_R;
            const float* bp = B + (n0 + c) * LORA_R;
            f32x4 t0 = *(const f32x4*)tp,       t1 = *(const f32x4*)(tp + 4);
            f32x4 t2 = *(const f32x4*)(tp + 8), t3 = *(const f32x4*)(tp + 12);
            f32x4 b0 = *(const f32x4*)bp,       b1 = *(const f32x4*)(bp + 4);
            f32x4 b2 = *(const f32x4*)(bp + 8), b3 = *(const f32x4*)(bp + 12);
            float lr = t0.x * b0.x + t0.y * b0.y + t0.z * b0.z + t0.w * b0.w
                     + t1.x * b1.x + t1.y * b1.y + t1.z * b1.z + t1.w * b1.w
                     + t2.x * b2.x + t2.y * b2.y + t2.z * b2.z + t2.w * b2.w
                     + t3.x * b3.x + t3.y * b3.y + t3.z * b3.z + t3.w * b3.w;
            v += 2.0f * lr;
        }
        unsafeAtomicAdd(&out[s * OUT_F + n0 + c], v);
    }
}

extern "C" void kernel_launch(void* const* d_in, const int* in_sizes, int n_in,
                              void* d_out, int out_size, void* d_ws, size_t ws_size,
                              hipStream_t stream) {
    const float* x      = (const float*)d_in[0];
    const int* packed   = (const int*)d_in[1];
    const float* scales = (const float*)d_in[2];
    const float* lora_A = (const float*)d_in[3];
    const float* lora_B = (const float*)d_in[4];
    float* out = (float*)d_out;

    unsigned short* xb = (unsigned short*)d_ws;                 // 1 MiB fp16 x
    float* t = (float*)((char*)d_ws + (size_t)SEQ * IN_F * 2);  // 4 KiB

    hipMemsetAsync(out, 0, (size_t)SEQ * OUT_F * sizeof(float), stream);
    k_prep<<<SEQ, 256, 0, stream>>>(x, lora_A, xb, t);
    k_main<<<512, 512, 0, stream>>>(packed, scales, xb, t, lora_B, out);
}